// Round 4
// baseline (85.201 us; speedup 1.0000x reference)
//
#include <hip/hip_runtime.h>
#include <hip/hip_fp16.h>

// MLPKANlayer: out[b][o] = sum_i g_n(x[b,i]), n = i*128+o,
//   g_n(x) = y_n(x)*ss_n + x*rs_n  (1->5->5->1 SiLU MLP). f32 in/out.
//
// R24 = R23 (o-quad table NSEG=32, packed index words uP, packed-f16
// accumulate, 1024-thr blocks) MINUS LDS staging: mlp_quad gathers uint4
// entries directly from the global table. Rationale: table is 2 MiB =
// fully L2-resident; i is wave-uniform so a wave's 64 lanes gather within
// ONE 512-B row (<=8 cache lines, broadcast) -> ~67 MB L2 traffic ~ 1.9us
// chip-wide, vs the DS pipe's ~3.2us/CU (gather + stage writes + 32 MiB
// staging reads + extra barrier). Frees 64 KiB LDS, one barrier. Guide
// common-mistake #7: don't LDS-stage what L2 already fits.
// Evidence: R21-23 VALU cuts hit diminishing returns (-2.9/-1.1/-0.4us) ->
// inner loop is DS/LDS-pipe-bound, not VALU-bound. Arithmetic bit-identical
// to R23 (absmax must stay 0.008789). Regression => revert to staging,
// declare practical floor.

constexpr int IN_SZ = 128, OUT_SZ = 128, BATCH = 2048, NSUB = IN_SZ * OUT_SZ;
constexpr int NSEG = 32;                       // segments; 33 knot values
constexpr float XMIN = -4.0f, XRANGE = 8.0f;
constexpr float STEP = XRANGE / (float)NSEG;   // 0.25
constexpr float INVH = (float)NSEG / XRANGE;   // 4
constexpr float UOFF = -XMIN * INVH;           // 16

__device__ __forceinline__ float silu_f(float z) {
  float t = __builtin_amdgcn_exp2f(z * -1.44269504088896f);   // exp(-z)
  return z * __builtin_amdgcn_rcpf(1.0f + t);
}

// pack one x value -> (fi*16)<<16 | f16(f)
__device__ __forceinline__ uint32_t pack_eval(float xv) {
  float u  = fmaf(xv, INVH, UOFF);
  float fi = __builtin_amdgcn_fmed3f(floorf(u), 0.0f, (float)(NSEG - 1));
  float f  = u - fi;                           // unclamped -> extrapolate
  uint32_t off = (uint32_t)((int)fi << 4);     // byte offset fi*16
  __half fh = __float2half_rn(f);
  return (off << 16) | (uint32_t)__half_as_ushort(fh);
}

// ---- k1 prep: build quad-table (blocks < 4096) + pack-transpose x ----------
// Build: 4 subnets x 64 lanes (k = 0..32 active); subnet wave-uniform ->
// weights are s_loads. After barrier, wave 0 packs uint4 entry
// {a01,a23,s01,s23} (half2 each) at tbl[((q*128 + i)*32 + k)]; q=o>>2=blk&31,
// i=blk>>5, consecutive-k lanes -> coalesced 16B stores.
// Transpose: uP[g][b] = packed words for x[b][4g..4g+3] (uint4-coalesced).
__global__ __launch_bounds__(256) void prep(
    const float* __restrict__ x,
    const float* __restrict__ w0, const float* __restrict__ b0,
    const float* __restrict__ w1, const float* __restrict__ b1,
    const float* __restrict__ w2, const float* __restrict__ b2,
    const float* __restrict__ ss, const float* __restrict__ rs,
    __half2* __restrict__ tbl, uint4* __restrict__ uP) {
  __shared__ float smem[64 * 65];
  const int tid = threadIdx.x;
  const int blk = blockIdx.x;

  if (blk < NSUB / 4) {
    float (*gv)[40] = (float (*)[40])smem;      // 4 subnets x 33 knots
    const int sl = __builtin_amdgcn_readfirstlane(tid >> 6);  // 0..3 uniform
    const int k  = tid & 63;
    const int n  = blk * 4 + sl;

    if (k <= NSEG) {
      const float xk = XMIN + (float)k * STEP;
      float h1[5], h2[5];
#pragma unroll
      for (int j = 0; j < 5; ++j)
        h1[j] = silu_f(fmaf(w0[n * 5 + j], xk, b0[n * 5 + j]));
#pragma unroll
      for (int j = 0; j < 5; ++j) {
        float z = b1[n * 5 + j];
#pragma unroll
        for (int kk = 0; kk < 5; ++kk)
          z = fmaf(w1[n * 25 + j * 5 + kk], h1[kk], z);
        h2[j] = silu_f(z);
      }
      float y = b2[n];
#pragma unroll
      for (int kk = 0; kk < 5; ++kk) y = fmaf(w2[n * 5 + kk], h2[kk], y);
      gv[sl][k] = fmaf(y, ss[n], xk * rs[n]);
    }
    __syncthreads();
    if (sl == 0 && k < NSEG) {
      float a0 = gv[0][k], a1 = gv[1][k], a2 = gv[2][k], a3 = gv[3][k];
      __half2 ent[4];
      ent[0] = __floats2half2_rn(a0, a1);                      // a01
      ent[1] = __floats2half2_rn(a2, a3);                      // a23
      ent[2] = __floats2half2_rn(gv[0][k + 1] - a0, gv[1][k + 1] - a1); // s01
      ent[3] = __floats2half2_rn(gv[2][k + 1] - a2, gv[3][k + 1] - a3); // s23
      size_t idx = (((size_t)(blk & 31) * IN_SZ) + (blk >> 5)) * NSEG + k;
      ((uint4*)tbl)[idx] = *(uint4*)ent;
    }
  } else {
    // pack-transpose: 64(b) x 64(i) tile
    float (*tile)[65] = (float (*)[65])smem;
    const int t   = blk - NSUB / 4;              // 0..63
    const int b0t = (t & 31) * 64;
    const int i0  = (t >> 5) * 64;
    const int l = tid & 63, w = tid >> 6;        // l = b-lane, w = 0..3
#pragma unroll
    for (int r = 0; r < 16; ++r) {
      int row = w + 4 * r;                       // b-local
      tile[row][l] = x[(size_t)(b0t + row) * IN_SZ + i0 + l];
    }
    __syncthreads();
#pragma unroll
    for (int r = 0; r < 4; ++r) {
      int g = w + 4 * r;                         // i-group local, 0..15
      uint4 v;
      v.x = pack_eval(tile[l][4 * g]);
      v.y = pack_eval(tile[l][4 * g + 1]);
      v.z = pack_eval(tile[l][4 * g + 2]);
      v.w = pack_eval(tile[l][4 * g + 3]);
      uP[(size_t)(i0 / 4 + g) * BATCH + b0t + l] = v;
    }
  }
}

// ---- k2 main: block = (o-quad, 128 rows) x 1024 thr = 8 i-eighths ----------
// No LDS staging: gather straight from L2-resident table. Wave-uniform i
// keeps each wave's 64 gathers inside one 512-B row.
__global__ __launch_bounds__(1024, 8) void mlp_quad(
    const uint4* __restrict__ uP, const uint4* __restrict__ tbl,
    float* __restrict__ out) {
  __shared__ float4 red[7 * 128];                // 14 KiB partials

  const int tid   = threadIdx.x;
  const int q     = blockIdx.x & 31;             // o-quad id
  const int chunk = blockIdx.x >> 5;             // 0..15 (128 rows each)

  const char* __restrict__ tq =
      (const char*)(tbl + (size_t)q * IN_SZ * NSEG);   // 64 KiB slab base

  const int rl  = tid & 127;                     // row-local, 0..127
  const int iq  = tid >> 7;                      // i-eighth (wave-uniform)
  const int row = chunk * 128 + rl;              // batch row
  const uint4* __restrict__ ucol = uP + (size_t)(iq * 4) * BATCH + row;

  __half2 c01 = __floats2half2_rn(0.0f, 0.0f);
  __half2 c23 = __floats2half2_rn(0.0f, 0.0f);
#pragma unroll
  for (int g = 0; g < 4; ++g) {                  // 4 groups x 4 i = 16 evals
    uint4 wv = ucol[(size_t)g * BATCH];          // 4 packed words, one dwordx4
    uint32_t ws[4] = { wv.x, wv.y, wv.z, wv.w };
#pragma unroll
    for (int j = 0; j < 4; ++j) {
      const int i = (iq * 4 + g) * 4 + j;        // absolute i (wave-uniform)
      const uint32_t w = ws[j];
      const uint32_t off = w >> 16;              // fi*16 byte offset
      union { uint32_t u; __half2 h2; } cv; cv.u = w;
      __half2 ff = __half2half2(__low2half(cv.h2));   // splat f
      uint4 hh = *(const uint4*)(tq + (size_t)i * (NSEG * 16) + off);
      c01 = __hfma2(*(__half2*)&hh.z, ff, __hadd2(c01, *(__half2*)&hh.x));
      c23 = __hfma2(*(__half2*)&hh.w, ff, __hadd2(c23, *(__half2*)&hh.y));
    }
  }
  float2 p01 = __half22float2(c01), p23 = __half22float2(c23);
  float a0 = p01.x, a1 = p01.y, a2 = p23.x, a3 = p23.y;

  // combine 8 i-eighths
  if (iq) red[(iq - 1) * 128 + rl] = make_float4(a0, a1, a2, a3);
  __syncthreads();
  if (!iq) {
    float4 res = make_float4(a0, a1, a2, a3);
#pragma unroll
    for (int r = 0; r < 7; ++r) {
      float4 p = red[r * 128 + rl];
      res.x += p.x; res.y += p.y; res.z += p.z; res.w += p.w;
    }
    *(float4*)&out[(size_t)row * OUT_SZ + 4 * q] = res;
  }
}

// ---- fallback (ws too small): exact raw-array kernel -----------------------
__global__ __launch_bounds__(512) void mlp_raw(
    const float* __restrict__ x,
    const float* __restrict__ w0, const float* __restrict__ b0,
    const float* __restrict__ w1, const float* __restrict__ b1,
    const float* __restrict__ w2, const float* __restrict__ b2,
    const float* __restrict__ ss, const float* __restrict__ rs,
    float* __restrict__ out) {
  __shared__ float red[256];
  const int tid  = threadIdx.x;
  const int wave = __builtin_amdgcn_readfirstlane(tid) >> 6;
  const int lane = tid & 63;
  const int half = wave >> 2;
  const int sub  = wave & 3;
  const int o     = blockIdx.x & (OUT_SZ - 1);
  const int chunk = blockIdx.x >> 7;
  const int b     = chunk * 256 + sub * 64 + lane;
  const int i0    = half * 64;
  const float4* __restrict__ xrow = (const float4*)(x + (size_t)b * IN_SZ + i0);
  float acc = 0.0f;
#pragma unroll 1
  for (int c = 0; c < 16; ++c) {
    float4 xv = xrow[c];
    float xs[4] = { xv.x, xv.y, xv.z, xv.w };
#pragma unroll
    for (int r = 0; r < 4; ++r) {
      int n = (i0 + c * 4 + r) * OUT_SZ + o;
      float h1[5], h2[5];
#pragma unroll
      for (int j = 0; j < 5; ++j)
        h1[j] = silu_f(fmaf(w0[n * 5 + j], xs[r], b0[n * 5 + j]));
#pragma unroll
      for (int j = 0; j < 5; ++j) {
        float z = b1[n * 5 + j];
#pragma unroll
        for (int k = 0; k < 5; ++k) z = fmaf(w1[n * 25 + j * 5 + k], h1[k], z);
        h2[j] = silu_f(z);
      }
      float y = b2[n];
#pragma unroll
      for (int k = 0; k < 5; ++k) y = fmaf(w2[n * 5 + k], h2[k], y);
      acc += fmaf(y, ss[n], xs[r] * rs[n]);
    }
  }
  if (half) red[sub * 64 + lane] = acc;
  __syncthreads();
  if (!half) out[(size_t)b * OUT_SZ + o] = acc + red[sub * 64 + lane];
}

extern "C" void kernel_launch(void* const* d_in, const int* in_sizes, int n_in,
                              void* d_out, int out_size, void* d_ws, size_t ws_size,
                              hipStream_t stream) {
  const float* x  = (const float*)d_in[0];
  const float* w0 = (const float*)d_in[1];
  const float* b0 = (const float*)d_in[2];
  const float* w1 = (const float*)d_in[3];
  const float* b1 = (const float*)d_in[4];
  const float* w2 = (const float*)d_in[5];
  const float* b2 = (const float*)d_in[6];
  const float* ss = (const float*)d_in[7];
  const float* rs = (const float*)d_in[8];

  const size_t TBL_BYTES = (size_t)NSUB * NSEG * sizeof(__half2);   // 2 MiB
  const size_t XT_BYTES  = (size_t)(IN_SZ / 4) * BATCH * sizeof(uint4); // 1 MiB

  if (ws_size >= TBL_BYTES + XT_BYTES) {
    __half2* tbl = (__half2*)d_ws;
    uint4*   uP  = (uint4*)((char*)d_ws + TBL_BYTES);
    prep<<<dim3(NSUB / 4 + 64), dim3(256), 0, stream>>>(
        x, w0, b0, w1, b1, w2, b2, ss, rs, tbl, uP);
    mlp_quad<<<dim3(32 * (BATCH / 128)), dim3(1024), 0, stream>>>(
        uP, (const uint4*)tbl, (float*)d_out);
  } else {
    mlp_raw<<<dim3(OUT_SZ * (BATCH / 256)), dim3(512), 0, stream>>>(
        x, w0, b0, w1, b1, w2, b2, ss, rs, (float*)d_out);
  }
}

// Round 5
// 82.869 us; speedup vs baseline: 1.0281x; 1.0281x over previous
//
#include <hip/hip_runtime.h>
#include <hip/hip_fp16.h>

// MLPKANlayer: out[b][o] = sum_i g_n(x[b,i]), n = i*128+o,
//   g_n(x) = y_n(x)*ss_n + x*rs_n  (1->5->5->1 SiLU MLP). f32 in/out.
//
// R25 = R23 (LDS-staged o-quad table NSEG=32, packed index words uP,
// packed-f16 accumulate, 1024-thr blocks, 8 waves/SIMD) + conflict-split
// gather: table entry 16B -> 2x8B sub-tables A={a01,s01}, B={a23,s23};
// eval does 2x ds_read_b64 instead of 1x ds_read_b128. Rationale: gather
// addr = i*512 + fi*16 with wave-uniform i puts all 64 lanes in one row;
// 16B granule = only 8 bank groups -> ~8-way alias (2.94x, m136) on the
// data-dependent fi ~ N(16,4). 8B granule = 16 groups -> ~4-way (1.58x).
// Same staged bytes, bit-identical arithmetic, same occupancy/grid.
// Evidence: R24's L2-direct gather REGRESSED +2.9us (VMEM scatter worse
// than DS) -> staging confirmed; R21-23 VALU cuts exhausted -> conflicts
// are the last modeled term (~6us/CU at 8-way). Null/regress here =>
// R23 is the practical floor, declare roofline.

constexpr int IN_SZ = 128, OUT_SZ = 128, BATCH = 2048, NSUB = IN_SZ * OUT_SZ;
constexpr int NSEG = 32;                       // segments; 33 knot values
constexpr float XMIN = -4.0f, XRANGE = 8.0f;
constexpr float STEP = XRANGE / (float)NSEG;   // 0.25
constexpr float INVH = (float)NSEG / XRANGE;   // 4
constexpr float UOFF = -XMIN * INVH;           // 16

__device__ __forceinline__ float silu_f(float z) {
  float t = __builtin_amdgcn_exp2f(z * -1.44269504088896f);   // exp(-z)
  return z * __builtin_amdgcn_rcpf(1.0f + t);
}

// pack one x value -> (fi*8)<<16 | f16(f)   (fi*8 = byte offset in 8B table)
__device__ __forceinline__ uint32_t pack_eval(float xv) {
  float u  = fmaf(xv, INVH, UOFF);
  float fi = __builtin_amdgcn_fmed3f(floorf(u), 0.0f, (float)(NSEG - 1));
  float f  = u - fi;                           // unclamped -> extrapolate
  uint32_t off = (uint32_t)((int)fi << 3);     // byte offset fi*8
  __half fh = __float2half_rn(f);
  return (off << 16) | (uint32_t)__half_as_ushort(fh);
}

// ---- k1 prep: build split tables (blocks < 4096) + pack-transpose x --------
// Build: 4 subnets x 64 lanes (k = 0..32 active); subnet wave-uniform ->
// weights are s_loads. After barrier, wave 0 writes 8B entries:
//   slab q (64 KiB at q*65536): A region [0,32K): (i*32+k)*8 -> {a01,s01}
//                               B region [32K,64K): same idx -> {a23,s23}
// q = o>>2 = blk&31, i = blk>>5; consecutive-k lanes -> coalesced 8B stores.
// Transpose: uP[g][b] = packed words for x[b][4g..4g+3] (uint4-coalesced).
__global__ __launch_bounds__(256) void prep(
    const float* __restrict__ x,
    const float* __restrict__ w0, const float* __restrict__ b0,
    const float* __restrict__ w1, const float* __restrict__ b1,
    const float* __restrict__ w2, const float* __restrict__ b2,
    const float* __restrict__ ss, const float* __restrict__ rs,
    uint2* __restrict__ tbl, uint4* __restrict__ uP) {
  __shared__ float smem[64 * 65];
  const int tid = threadIdx.x;
  const int blk = blockIdx.x;

  if (blk < NSUB / 4) {
    float (*gv)[40] = (float (*)[40])smem;      // 4 subnets x 33 knots
    const int sl = __builtin_amdgcn_readfirstlane(tid >> 6);  // 0..3 uniform
    const int k  = tid & 63;
    const int n  = blk * 4 + sl;

    if (k <= NSEG) {
      const float xk = XMIN + (float)k * STEP;
      float h1[5], h2[5];
#pragma unroll
      for (int j = 0; j < 5; ++j)
        h1[j] = silu_f(fmaf(w0[n * 5 + j], xk, b0[n * 5 + j]));
#pragma unroll
      for (int j = 0; j < 5; ++j) {
        float z = b1[n * 5 + j];
#pragma unroll
        for (int kk = 0; kk < 5; ++kk)
          z = fmaf(w1[n * 25 + j * 5 + kk], h1[kk], z);
        h2[j] = silu_f(z);
      }
      float y = b2[n];
#pragma unroll
      for (int kk = 0; kk < 5; ++kk) y = fmaf(w2[n * 5 + kk], h2[kk], y);
      gv[sl][k] = fmaf(y, ss[n], xk * rs[n]);
    }
    __syncthreads();
    if (sl == 0 && k < NSEG) {
      float a0 = gv[0][k], a1 = gv[1][k], a2 = gv[2][k], a3 = gv[3][k];
      __half2 eA[2], eB[2];
      eA[0] = __floats2half2_rn(a0, a1);                           // a01
      eA[1] = __floats2half2_rn(gv[0][k + 1] - a0, gv[1][k + 1] - a1); // s01
      eB[0] = __floats2half2_rn(a2, a3);                           // a23
      eB[1] = __floats2half2_rn(gv[2][k + 1] - a2, gv[3][k + 1] - a3); // s23
      size_t idxA = ((size_t)(blk & 31) * 8192) + (size_t)(blk >> 5) * 32 + k;
      tbl[idxA]        = *(uint2*)eA;
      tbl[idxA + 4096] = *(uint2*)eB;
    }
  } else {
    // pack-transpose: 64(b) x 64(i) tile
    float (*tile)[65] = (float (*)[65])smem;
    const int t   = blk - NSUB / 4;              // 0..63
    const int b0t = (t & 31) * 64;
    const int i0  = (t >> 5) * 64;
    const int l = tid & 63, w = tid >> 6;        // l = b-lane, w = 0..3
#pragma unroll
    for (int r = 0; r < 16; ++r) {
      int row = w + 4 * r;                       // b-local
      tile[row][l] = x[(size_t)(b0t + row) * IN_SZ + i0 + l];
    }
    __syncthreads();
#pragma unroll
    for (int r = 0; r < 4; ++r) {
      int g = w + 4 * r;                         // i-group local, 0..15
      uint4 v;
      v.x = pack_eval(tile[l][4 * g]);
      v.y = pack_eval(tile[l][4 * g + 1]);
      v.z = pack_eval(tile[l][4 * g + 2]);
      v.w = pack_eval(tile[l][4 * g + 3]);
      uP[(size_t)(i0 / 4 + g) * BATCH + b0t + l] = v;
    }
  }
}

// ---- k2 main: block = (o-quad, 128 rows) x 1024 thr = 8 i-eighths ----------
__global__ __launch_bounds__(1024, 8) void mlp_quad(
    const uint4* __restrict__ uP, const uint4* __restrict__ tbl,
    float* __restrict__ out) {
  __shared__ uint4 ts[IN_SZ * NSEG];   // 64 KiB: A sub-table [0,32K), B [32K,64K)

  const int tid   = threadIdx.x;
  const int q     = blockIdx.x & 31;             // o-quad id
  const int chunk = blockIdx.x >> 5;             // 0..15 (128 rows each)

  // stage quad slab: 64 KiB = 4096 uint4, 4 per thread, coalesced
  {
    const uint4* __restrict__ s4 = tbl + (size_t)q * IN_SZ * NSEG;
#pragma unroll
    for (int r = 0; r < 4; ++r) ts[tid + 1024 * r] = s4[tid + 1024 * r];
  }
  __syncthreads();

  const int rl  = tid & 127;                     // row-local, 0..127
  const int iq  = tid >> 7;                      // i-eighth (wave-uniform)
  const int row = chunk * 128 + rl;              // batch row
  const uint4* __restrict__ ucol = uP + (size_t)(iq * 4) * BATCH + row;
  const char* __restrict__ lb = (const char*)ts;

  __half2 c01 = __floats2half2_rn(0.0f, 0.0f);
  __half2 c23 = __floats2half2_rn(0.0f, 0.0f);
#pragma unroll
  for (int g = 0; g < 4; ++g) {                  // 4 groups x 4 i = 16 evals
    uint4 wv = ucol[(size_t)g * BATCH];          // 4 packed words, one dwordx4
    uint32_t ws[4] = { wv.x, wv.y, wv.z, wv.w };
#pragma unroll
    for (int j = 0; j < 4; ++j) {
      const int i = (iq * 4 + g) * 4 + j;        // absolute i (wave-uniform)
      const uint32_t w = ws[j];
      const uint32_t off = w >> 16;              // fi*8 byte offset
      union { uint32_t u; __half2 h2; } cv; cv.u = w;
      __half2 ff = __half2half2(__low2half(cv.h2));   // splat f
      uint2 eA = *(const uint2*)(lb + (size_t)i * 256 + off);           // {a01,s01}
      uint2 eB = *(const uint2*)(lb + 32768 + (size_t)i * 256 + off);   // {a23,s23}
      c01 = __hfma2(*(__half2*)&eA.y, ff, __hadd2(c01, *(__half2*)&eA.x));
      c23 = __hfma2(*(__half2*)&eB.y, ff, __hadd2(c23, *(__half2*)&eB.x));
    }
  }
  float2 p01 = __half22float2(c01), p23 = __half22float2(c23);
  float a0 = p01.x, a1 = p01.y, a2 = p23.x, a3 = p23.y;

  // combine 8 i-eighths: reuse table LDS after all waves pass the barrier
  __syncthreads();
  float4* red = (float4*)ts;                     // [7][128] partials
  if (iq) red[(iq - 1) * 128 + rl] = make_float4(a0, a1, a2, a3);
  __syncthreads();
  if (!iq) {
    float4 res = make_float4(a0, a1, a2, a3);
#pragma unroll
    for (int r = 0; r < 7; ++r) {
      float4 p = red[r * 128 + rl];
      res.x += p.x; res.y += p.y; res.z += p.z; res.w += p.w;
    }
    *(float4*)&out[(size_t)row * OUT_SZ + 4 * q] = res;
  }
}

// ---- fallback (ws too small): exact raw-array kernel -----------------------
__global__ __launch_bounds__(512) void mlp_raw(
    const float* __restrict__ x,
    const float* __restrict__ w0, const float* __restrict__ b0,
    const float* __restrict__ w1, const float* __restrict__ b1,
    const float* __restrict__ w2, const float* __restrict__ b2,
    const float* __restrict__ ss, const float* __restrict__ rs,
    float* __restrict__ out) {
  __shared__ float red[256];
  const int tid  = threadIdx.x;
  const int wave = __builtin_amdgcn_readfirstlane(tid) >> 6;
  const int lane = tid & 63;
  const int half = wave >> 2;
  const int sub  = wave & 3;
  const int o     = blockIdx.x & (OUT_SZ - 1);
  const int chunk = blockIdx.x >> 7;
  const int b     = chunk * 256 + sub * 64 + lane;
  const int i0    = half * 64;
  const float4* __restrict__ xrow = (const float4*)(x + (size_t)b * IN_SZ + i0);
  float acc = 0.0f;
#pragma unroll 1
  for (int c = 0; c < 16; ++c) {
    float4 xv = xrow[c];
    float xs[4] = { xv.x, xv.y, xv.z, xv.w };
#pragma unroll
    for (int r = 0; r < 4; ++r) {
      int n = (i0 + c * 4 + r) * OUT_SZ + o;
      float h1[5], h2[5];
#pragma unroll
      for (int j = 0; j < 5; ++j)
        h1[j] = silu_f(fmaf(w0[n * 5 + j], xs[r], b0[n * 5 + j]));
#pragma unroll
      for (int j = 0; j < 5; ++j) {
        float z = b1[n * 5 + j];
#pragma unroll
        for (int k = 0; k < 5; ++k) z = fmaf(w1[n * 25 + j * 5 + k], h1[k], z);
        h2[j] = silu_f(z);
      }
      float y = b2[n];
#pragma unroll
      for (int k = 0; k < 5; ++k) y = fmaf(w2[n * 5 + k], h2[k], y);
      acc += fmaf(y, ss[n], xs[r] * rs[n]);
    }
  }
  if (half) red[sub * 64 + lane] = acc;
  __syncthreads();
  if (!half) out[(size_t)b * OUT_SZ + o] = acc + red[sub * 64 + lane];
}

extern "C" void kernel_launch(void* const* d_in, const int* in_sizes, int n_in,
                              void* d_out, int out_size, void* d_ws, size_t ws_size,
                              hipStream_t stream) {
  const float* x  = (const float*)d_in[0];
  const float* w0 = (const float*)d_in[1];
  const float* b0 = (const float*)d_in[2];
  const float* w1 = (const float*)d_in[3];
  const float* b1 = (const float*)d_in[4];
  const float* w2 = (const float*)d_in[5];
  const float* b2 = (const float*)d_in[6];
  const float* ss = (const float*)d_in[7];
  const float* rs = (const float*)d_in[8];

  const size_t TBL_BYTES = (size_t)NSUB * NSEG * 8;                 // 2 MiB
  const size_t XT_BYTES  = (size_t)(IN_SZ / 4) * BATCH * sizeof(uint4); // 1 MiB

  if (ws_size >= TBL_BYTES + XT_BYTES) {
    uint2* tbl = (uint2*)d_ws;
    uint4* uP  = (uint4*)((char*)d_ws + TBL_BYTES);
    prep<<<dim3(NSUB / 4 + 64), dim3(256), 0, stream>>>(
        x, w0, b0, w1, b1, w2, b2, ss, rs, tbl, uP);
    mlp_quad<<<dim3(32 * (BATCH / 128)), dim3(1024), 0, stream>>>(
        uP, (const uint4*)tbl, (float*)d_out);
  } else {
    mlp_raw<<<dim3(OUT_SZ * (BATCH / 256)), dim3(512), 0, stream>>>(
        x, w0, b0, w1, b1, w2, b2, ss, rs, (float*)d_out);
  }
}

// Round 6
// 81.429 us; speedup vs baseline: 1.0463x; 1.0177x over previous
//
#include <hip/hip_runtime.h>
#include <hip/hip_fp16.h>

// MLPKANlayer: out[b][o] = sum_i g_n(x[b,i]), n = i*128+o,
//   g_n(x) = y_n(x)*ss_n + x*rs_n  (1->5->5->1 SiLU MLP). f32 in/out.
//
// R26 = R23 verbatim (best measured: 82.29us). Session-final revert after
// the two pre-committed forks both resolved negative:
//   R24 (drop LDS staging, gather from L2): +2.9us REGRESS -> staging wins.
//   R25 (split 16B->2x8B gather vs bank conflicts): +0.6us NULL -> conflicts
//        not the dominant term; extra DS issue cancels relief.
// Structure: o-quad table NSEG=32 over [-4,4], entries {a01,a23,s01,s23}
// (half2 x4 = 16B, one ds_read_b128 serves 4 outputs); index math hoisted
// to prep (uP packs (fi*16)<<16|f16(f) per (b,i)); packed-f16 accumulate
// (2x pk_add + 2x pk_fma per eval); 1024-thr blocks, 2 blocks/CU,
// 8 waves/SIMD. Ladder: 86.7 -> 83.8 (pk-f16) -> 82.7 (occupancy) ->
// 82.3 (hoisted index). absmax 0.008789 (budget 0.0225).

constexpr int IN_SZ = 128, OUT_SZ = 128, BATCH = 2048, NSUB = IN_SZ * OUT_SZ;
constexpr int NSEG = 32;                       // segments; 33 knot values
constexpr float XMIN = -4.0f, XRANGE = 8.0f;
constexpr float STEP = XRANGE / (float)NSEG;   // 0.25
constexpr float INVH = (float)NSEG / XRANGE;   // 4
constexpr float UOFF = -XMIN * INVH;           // 16

__device__ __forceinline__ float silu_f(float z) {
  float t = __builtin_amdgcn_exp2f(z * -1.44269504088896f);   // exp(-z)
  return z * __builtin_amdgcn_rcpf(1.0f + t);
}

// pack one x value -> (fi*16)<<16 | f16(f)
__device__ __forceinline__ uint32_t pack_eval(float xv) {
  float u  = fmaf(xv, INVH, UOFF);
  float fi = __builtin_amdgcn_fmed3f(floorf(u), 0.0f, (float)(NSEG - 1));
  float f  = u - fi;                           // unclamped -> extrapolate
  uint32_t off = (uint32_t)((int)fi << 4);     // byte offset fi*16
  __half fh = __float2half_rn(f);
  return (off << 16) | (uint32_t)__half_as_ushort(fh);
}

// ---- k1 prep: build quad-table (blocks < 4096) + pack-transpose x ----------
// Build: 4 subnets x 64 lanes (k = 0..32 active); subnet wave-uniform ->
// weights are s_loads. After barrier, wave 0 packs uint4 entry
// {a01,a23,s01,s23} (half2 each) at tbl[((q*128 + i)*32 + k)]; q=o>>2=blk&31,
// i=blk>>5, consecutive-k lanes -> coalesced 16B stores.
// Transpose: uP[g][b] = packed words for x[b][4g..4g+3] (uint4-coalesced).
__global__ __launch_bounds__(256) void prep(
    const float* __restrict__ x,
    const float* __restrict__ w0, const float* __restrict__ b0,
    const float* __restrict__ w1, const float* __restrict__ b1,
    const float* __restrict__ w2, const float* __restrict__ b2,
    const float* __restrict__ ss, const float* __restrict__ rs,
    __half2* __restrict__ tbl, uint4* __restrict__ uP) {
  __shared__ float smem[64 * 65];
  const int tid = threadIdx.x;
  const int blk = blockIdx.x;

  if (blk < NSUB / 4) {
    float (*gv)[40] = (float (*)[40])smem;      // 4 subnets x 33 knots
    const int sl = __builtin_amdgcn_readfirstlane(tid >> 6);  // 0..3 uniform
    const int k  = tid & 63;
    const int n  = blk * 4 + sl;

    if (k <= NSEG) {
      const float xk = XMIN + (float)k * STEP;
      float h1[5], h2[5];
#pragma unroll
      for (int j = 0; j < 5; ++j)
        h1[j] = silu_f(fmaf(w0[n * 5 + j], xk, b0[n * 5 + j]));
#pragma unroll
      for (int j = 0; j < 5; ++j) {
        float z = b1[n * 5 + j];
#pragma unroll
        for (int kk = 0; kk < 5; ++kk)
          z = fmaf(w1[n * 25 + j * 5 + kk], h1[kk], z);
        h2[j] = silu_f(z);
      }
      float y = b2[n];
#pragma unroll
      for (int kk = 0; kk < 5; ++kk) y = fmaf(w2[n * 5 + kk], h2[kk], y);
      gv[sl][k] = fmaf(y, ss[n], xk * rs[n]);
    }
    __syncthreads();
    if (sl == 0 && k < NSEG) {
      float a0 = gv[0][k], a1 = gv[1][k], a2 = gv[2][k], a3 = gv[3][k];
      __half2 ent[4];
      ent[0] = __floats2half2_rn(a0, a1);                      // a01
      ent[1] = __floats2half2_rn(a2, a3);                      // a23
      ent[2] = __floats2half2_rn(gv[0][k + 1] - a0, gv[1][k + 1] - a1); // s01
      ent[3] = __floats2half2_rn(gv[2][k + 1] - a2, gv[3][k + 1] - a3); // s23
      size_t idx = (((size_t)(blk & 31) * IN_SZ) + (blk >> 5)) * NSEG + k;
      ((uint4*)tbl)[idx] = *(uint4*)ent;
    }
  } else {
    // pack-transpose: 64(b) x 64(i) tile
    float (*tile)[65] = (float (*)[65])smem;
    const int t   = blk - NSUB / 4;              // 0..63
    const int b0t = (t & 31) * 64;
    const int i0  = (t >> 5) * 64;
    const int l = tid & 63, w = tid >> 6;        // l = b-lane, w = 0..3
#pragma unroll
    for (int r = 0; r < 16; ++r) {
      int row = w + 4 * r;                       // b-local
      tile[row][l] = x[(size_t)(b0t + row) * IN_SZ + i0 + l];
    }
    __syncthreads();
#pragma unroll
    for (int r = 0; r < 4; ++r) {
      int g = w + 4 * r;                         // i-group local, 0..15
      uint4 v;
      v.x = pack_eval(tile[l][4 * g]);
      v.y = pack_eval(tile[l][4 * g + 1]);
      v.z = pack_eval(tile[l][4 * g + 2]);
      v.w = pack_eval(tile[l][4 * g + 3]);
      uP[(size_t)(i0 / 4 + g) * BATCH + b0t + l] = v;
    }
  }
}

// ---- k2 main: block = (o-quad, 128 rows) x 1024 thr = 8 i-eighths ----------
__global__ __launch_bounds__(1024, 8) void mlp_quad(
    const uint4* __restrict__ uP, const uint4* __restrict__ tbl,
    float* __restrict__ out) {
  __shared__ uint4 ts[IN_SZ * NSEG];   // 64 KiB: [i][k] -> {a01,a23,s01,s23}

  const int tid   = threadIdx.x;
  const int q     = blockIdx.x & 31;             // o-quad id
  const int chunk = blockIdx.x >> 5;             // 0..15 (128 rows each)

  // stage quad slab: 64 KiB = 4096 uint4, 4 per thread, coalesced
  {
    const uint4* __restrict__ s4 = tbl + (size_t)q * IN_SZ * NSEG;
#pragma unroll
    for (int r = 0; r < 4; ++r) ts[tid + 1024 * r] = s4[tid + 1024 * r];
  }
  __syncthreads();

  const int rl  = tid & 127;                     // row-local, 0..127
  const int iq  = tid >> 7;                      // i-eighth (wave-uniform)
  const int row = chunk * 128 + rl;              // batch row
  const uint4* __restrict__ ucol = uP + (size_t)(iq * 4) * BATCH + row;

  __half2 c01 = __floats2half2_rn(0.0f, 0.0f);
  __half2 c23 = __floats2half2_rn(0.0f, 0.0f);
#pragma unroll
  for (int g = 0; g < 4; ++g) {                  // 4 groups x 4 i = 16 evals
    uint4 wv = ucol[(size_t)g * BATCH];          // 4 packed words, one dwordx4
    uint32_t ws[4] = { wv.x, wv.y, wv.z, wv.w };
#pragma unroll
    for (int j = 0; j < 4; ++j) {
      const int i = (iq * 4 + g) * 4 + j;        // absolute i
      const uint32_t w = ws[j];
      const uint32_t off = w >> 16;              // fi*16 byte offset
      union { uint32_t u; __half2 h2; } cv; cv.u = w;
      __half2 ff = __half2half2(__low2half(cv.h2));   // splat f (op_sel)
      uint4 hh = *(const uint4*)((const char*)ts + (size_t)i * (NSEG * 16) + off);
      c01 = __hfma2(*(__half2*)&hh.z, ff, __hadd2(c01, *(__half2*)&hh.x));
      c23 = __hfma2(*(__half2*)&hh.w, ff, __hadd2(c23, *(__half2*)&hh.y));
    }
  }
  float2 p01 = __half22float2(c01), p23 = __half22float2(c23);
  float a0 = p01.x, a1 = p01.y, a2 = p23.x, a3 = p23.y;

  // combine 8 i-eighths: reuse table LDS after all waves pass the barrier
  __syncthreads();
  float4* red = (float4*)ts;                     // [7][128] partials
  if (iq) red[(iq - 1) * 128 + rl] = make_float4(a0, a1, a2, a3);
  __syncthreads();
  if (!iq) {
    float4 res = make_float4(a0, a1, a2, a3);
#pragma unroll
    for (int r = 0; r < 7; ++r) {
      float4 p = red[r * 128 + rl];
      res.x += p.x; res.y += p.y; res.z += p.z; res.w += p.w;
    }
    *(float4*)&out[(size_t)row * OUT_SZ + 4 * q] = res;
  }
}

// ---- fallback (ws too small): exact raw-array kernel -----------------------
__global__ __launch_bounds__(512) void mlp_raw(
    const float* __restrict__ x,
    const float* __restrict__ w0, const float* __restrict__ b0,
    const float* __restrict__ w1, const float* __restrict__ b1,
    const float* __restrict__ w2, const float* __restrict__ b2,
    const float* __restrict__ ss, const float* __restrict__ rs,
    float* __restrict__ out) {
  __shared__ float red[256];
  const int tid  = threadIdx.x;
  const int wave = __builtin_amdgcn_readfirstlane(tid) >> 6;
  const int lane = tid & 63;
  const int half = wave >> 2;
  const int sub  = wave & 3;
  const int o     = blockIdx.x & (OUT_SZ - 1);
  const int chunk = blockIdx.x >> 7;
  const int b     = chunk * 256 + sub * 64 + lane;
  const int i0    = half * 64;
  const float4* __restrict__ xrow = (const float4*)(x + (size_t)b * IN_SZ + i0);
  float acc = 0.0f;
#pragma unroll 1
  for (int c = 0; c < 16; ++c) {
    float4 xv = xrow[c];
    float xs[4] = { xv.x, xv.y, xv.z, xv.w };
#pragma unroll
    for (int r = 0; r < 4; ++r) {
      int n = (i0 + c * 4 + r) * OUT_SZ + o;
      float h1[5], h2[5];
#pragma unroll
      for (int j = 0; j < 5; ++j)
        h1[j] = silu_f(fmaf(w0[n * 5 + j], xs[r], b0[n * 5 + j]));
#pragma unroll
      for (int j = 0; j < 5; ++j) {
        float z = b1[n * 5 + j];
#pragma unroll
        for (int k = 0; k < 5; ++k) z = fmaf(w1[n * 25 + j * 5 + k], h1[k], z);
        h2[j] = silu_f(z);
      }
      float y = b2[n];
#pragma unroll
      for (int k = 0; k < 5; ++k) y = fmaf(w2[n * 5 + k], h2[k], y);
      acc += fmaf(y, ss[n], xs[r] * rs[n]);
    }
  }
  if (half) red[sub * 64 + lane] = acc;
  __syncthreads();
  if (!half) out[(size_t)b * OUT_SZ + o] = acc + red[sub * 64 + lane];
}

extern "C" void kernel_launch(void* const* d_in, const int* in_sizes, int n_in,
                              void* d_out, int out_size, void* d_ws, size_t ws_size,
                              hipStream_t stream) {
  const float* x  = (const float*)d_in[0];
  const float* w0 = (const float*)d_in[1];
  const float* b0 = (const float*)d_in[2];
  const float* w1 = (const float*)d_in[3];
  const float* b1 = (const float*)d_in[4];
  const float* w2 = (const float*)d_in[5];
  const float* b2 = (const float*)d_in[6];
  const float* ss = (const float*)d_in[7];
  const float* rs = (const float*)d_in[8];

  const size_t TBL_BYTES = (size_t)NSUB * NSEG * sizeof(__half2);   // 2 MiB
  const size_t XT_BYTES  = (size_t)(IN_SZ / 4) * BATCH * sizeof(uint4); // 1 MiB

  if (ws_size >= TBL_BYTES + XT_BYTES) {
    __half2* tbl = (__half2*)d_ws;
    uint4*   uP  = (uint4*)((char*)d_ws + TBL_BYTES);
    prep<<<dim3(NSUB / 4 + 64), dim3(256), 0, stream>>>(
        x, w0, b0, w1, b1, w2, b2, ss, rs, tbl, uP);
    mlp_quad<<<dim3(32 * (BATCH / 128)), dim3(1024), 0, stream>>>(
        uP, (const uint4*)tbl, (float*)d_out);
  } else {
    mlp_raw<<<dim3(OUT_SZ * (BATCH / 256)), dim3(512), 0, stream>>>(
        x, w0, b0, w1, b1, w2, b2, ss, rs, (float*)d_out);
  }
}